// Round 14
// baseline (109.830 us; speedup 1.0000x reference)
//
#include <hip/hip_runtime.h>
#include <math.h>

// ---------------- problem constants ----------------
#define NB 8          // batch
#define NM 16         // modes
#define NPH 8         // photons
#define NSTATES 12870 // C(16,8)
#define NSUB 256      // 2^NPH column subsets
#define OUTS 128
#define NTILES 824    // sum over classes of ceil(R/4)*ceil(C/4)
#define NSLOTS (NTILES*16) // 13184
#define NSG 32        // s-groups of 8
#define SPH 8         // s per producer block
#define NTG 4         // tile groups
#define TILES_PER_TG 206
#define NGRID 1024    // NB * NSG * NTG
#define SLOTS_P2 32
#define NP2 412       // 412*32 == NSLOTS

// ---------------- compile-time tables ----------------
struct Tables {
  int binom[17][9];
  unsigned char cls_masks[256];
  int cls_off[10];
  int nt1[9], nt2[9];
  int tile_off[10];
};

constexpr int cpopc(int x){ int c=0; while(x){ c += x & 1; x >>= 1; } return c; }

constexpr Tables make_tables(){
  Tables t{};
  for (int n=0;n<=16;n++)
    for (int k=0;k<=8;k++){
      if (k==0) t.binom[n][k]=1;
      else if (n==0) t.binom[n][k]=0;
      else t.binom[n][k]=t.binom[n-1][k-1]+t.binom[n-1][k];
    }
  int idx=0;
  for (int p=0;p<=8;p++){
    t.cls_off[p]=idx;
    for (int m=0;m<256;m++) if (cpopc(m)==p) t.cls_masks[idx++]=(unsigned char)m;
  }
  t.cls_off[9]=idx; // 256
  int toff=0;
  for (int c=0;c<=8;c++){
    int R=t.binom[8][c], C=t.binom[8][8-c];
    t.nt1[c]=(R+3)/4; t.nt2[c]=(C+3)/4;
    t.tile_off[c]=toff; toff += t.nt1[c]*t.nt2[c];
  }
  t.tile_off[9]=toff;
  return t;
}

constexpr Tables HTBL = make_tables();
static_assert(HTBL.tile_off[9]==NTILES, "tile count");
static_assert(HTBL.cls_off[9]==256, "mask count");
__device__ const Tables TBL = HTBL;

// ---------------- workspace layout (bytes) ----------------
#define WS_TMAP   256               // NSLOTS ints = 52736 -> 52992 (pads never read)
#define WS_BSUM2  53248             // [NP2][NB] float = 13184 -> 66432
#define WS_POUT2  66560             // [NP2][NB*OUTS] float = 1687552 -> 1754112
#define WS_PART   1757184           // [NB][NSG][NSLOTS] float2 = 27000832

// ---------------- complex helpers ----------------
__device__ __forceinline__ float2 cmul(float2 a, float2 b){
  return make_float2(fmaf(a.x,b.x,-(a.y*b.y)), fmaf(a.x,b.y, a.y*b.x));
}
__device__ __forceinline__ void cmac(float2& acc, float2 a, float2 b){
  acc.x = fmaf(a.x, b.x, acc.x); acc.x = fmaf(-a.y, b.y, acc.x);
  acc.y = fmaf(a.x, b.y, acc.y); acc.y = fmaf(a.y, b.x, acc.y);
}

// ============ K1: fused setup + Ryser main, SPH=8 / 4 blocks per CU ========
// grid 1024 = NB(8) x NSG(32) x NTG(4); 33.1 KB LDS, 256 thr -> 4 blocks/CU
// (16 waves/CU vs R13's 8) to hide the combine's LDS gather conflicts.
// Fill: 16-value register DP per thread (chunk = t bits 4..7, multiply order
// v7,v6,v5,v4 then bits-0..3 DP == prior order -> bit-identical results).
__global__ __launch_bounds__(256, 4) void k_p1(
    const float* __restrict__ x, const float* __restrict__ th1,
    const float* __restrict__ th2, const float* __restrict__ mr,
    const float* __restrict__ mi, const int* __restrict__ rows, char* ws)
{
  __shared__ float2 P[16][256];      // 32 KB; row ts = table*8+s, col swizzled
  __shared__ float2 UinL[NM][NPH];   // 1 KB (dedicated)
  __shared__ float2 exL[NM];         // 128 B
  float2* __restrict__ part = (float2*)(ws + WS_PART);
  int tid = threadIdx.x;
  int blk = blockIdx.x;
  int b = blk >> 7, rest = blk & 127, sg = rest >> 2, tg = rest & 3;
  int sbase = sg * SPH;

  // prologue scratch aliased over P (all readers done by barrier 3)
  float2 (*T1)[NM]  = reinterpret_cast<float2(*)[NM]>(P[0]);
  float2 (*T2)[NM]  = reinterpret_cast<float2(*)[NM]>(P[1]);
  float2 (*Am)[NM]  = reinterpret_cast<float2(*)[NM]>(P[2]);
  float2 (*Bm)[NM]  = reinterpret_cast<float2(*)[NM]>(P[3]);

  // ---- phase A: T1/T2 + ex ----
  {
    int r = tid >> 4, cc = tid & 15;
    float sn, cs;
    sincosf(th1[r], &sn, &cs);
    float a = mr[0*256 + tid], bb = mi[0*256 + tid];
    T1[r][cc] = make_float2(cs*a - sn*bb, cs*bb + sn*a);
    sincosf(th2[r], &sn, &cs);
    float a2 = mr[2*256 + tid], b2 = mi[2*256 + tid];
    T2[r][cc] = make_float2(cs*a2 - sn*b2, cs*b2 + sn*a2);
    if (tid < NM){ float s2, c2; sincosf(x[b*NM + tid], &s2, &c2); exL[tid] = make_float2(c2, s2); }
  }
  __syncthreads();   // barrier 1

  // ---- phase B: Am/Bm with vectorized row loads ----
  {
    int r = tid >> 4, cc = tid & 15;
    float m1r[16], m1i[16], m3r[16], m3i[16];
    {
      const float4* p1r = (const float4*)(mr + 1*256 + r*16);
      const float4* p1i = (const float4*)(mi + 1*256 + r*16);
      const float4* p3r = (const float4*)(mr + 3*256 + r*16);
      const float4* p3i = (const float4*)(mi + 3*256 + r*16);
      #pragma unroll
      for (int q=0;q<4;q++){
        *(float4*)&m1r[q*4] = p1r[q];
        *(float4*)&m1i[q*4] = p1i[q];
        *(float4*)&m3r[q*4] = p3r[q];
        *(float4*)&m3i[q*4] = p3i[q];
      }
    }
    float2 accA = make_float2(0,0), accB = make_float2(0,0);
    #pragma unroll
    for (int m=0;m<NM;m++){
      cmac(accA, make_float2(m1r[m], m1i[m]), T1[m][cc]);
      cmac(accB, make_float2(m3r[m], m3i[m]), T2[m][cc]);
    }
    Am[r][cc] = accA; Bm[r][cc] = accB;
  }
  __syncthreads();   // barrier 2

  // ---- phase C: Uin with EA folded inline (bit-identical order) ----
  if (tid < NM*NPH){
    int p = tid >> 3, n = tid & 7;
    float2 acc = make_float2(0,0);
    #pragma unroll
    for (int m=0;m<NM;m++) cmac(acc, Bm[p][m], cmul(exL[m], Am[m][n]));
    UinL[p][n] = acc;
  }
  __syncthreads();   // barrier 3: scratch P[0..3] dead; UinL ready

  // ---- phase D: V-extract -> 16-value register-DP fill ----
  int ts = tid & 15;                 // row: table*8 + s
  int table = ts >> 3, sl = ts & 7;
  int sv = sbase + sl;
  {
    float2 v[8];
    #pragma unroll
    for (int j=0;j<8;j++){
      float2 a = make_float2(0,0);
      int m = table*8 + j;
      #pragma unroll
      for (int jj=0;jj<NPH;jj++)
        if ((sv>>jj) & 1){ a.x += UinL[m][jj].x; a.y += UinL[m][jj].y; }
      v[j] = a;
    }
    int chunk = tid >> 4;            // t bits 4..7
    int t0 = chunk << 4;
    int swz = (ts & 7) << 1;         // XOR on t bits 1..3 (bit0 preserved)
    float2 ph = make_float2((table==0 && (__popc(sv)&1)) ? -1.0f : 1.0f, 0.0f);
    if (chunk & 8) ph = cmul(ph, v[7]);
    if (chunk & 4) ph = cmul(ph, v[6]);
    if (chunk & 2) ph = cmul(ph, v[5]);
    if (chunk & 1) ph = cmul(ph, v[4]);

    float2 pl[16];
    pl[0] = ph;
    #pragma unroll
    for (int w=1; w<16; w++){
      int par = w & (w-1);
      int lb = (w&1) ? 0 : ((w&2) ? 1 : ((w&4) ? 2 : 3));
      pl[w] = cmul(pl[par], v[lb]);
    }
    #pragma unroll
    for (int w=0; w<16; w+=2){
      int tc = (t0 + w) ^ swz;
      *(float4*)&P[ts][tc] = make_float4(pl[w].x, pl[w].y, pl[w+1].x, pl[w+1].y);
    }
  }

  // ---- tmap ranking: hoisted (independent of P; overlaps barrier wait) ----
  if (tg == 3){
    int idx = blk >> 2;              // 0..255
    int kb = idx * 51;
    int ke = min(NSTATES, kb + 51);
    int k = kb + tid;
    if (k < ke){
      int t1=0, t2=0;
      #pragma unroll
      for (int i=0;i<NPH;i++){
        int rr = rows[k*NPH+i];
        if (rr < 8) t1 |= 1 << rr; else t2 |= 1 << (rr-8);
      }
      int c1 = __popc(t1);
      int rk1=0, cnt=0;
      #pragma unroll
      for (int bb=0;bb<8;bb++) if ((t1>>bb)&1){ cnt++; rk1 += TBL.binom[bb][cnt]; }
      int rk2=0; cnt=0;
      #pragma unroll
      for (int bb=0;bb<8;bb++) if ((t2>>bb)&1){ cnt++; rk2 += TBL.binom[bb][cnt]; }
      int tl = TBL.tile_off[c1] + (rk1>>2)*TBL.nt2[c1] + (rk2>>2);
      int slot = ((rk1&3)<<2) | (rk2&3);
      ((int*)(ws + WS_TMAP))[tl*16 + slot] = k;
    }
  }

  // combine-thread tile masks (registers + const tables only)
  bool active = tid < TILES_PER_TG;
  int tile = tg + 4*tid;
  int t1v[4] = {0,0,0,0}, t2v[4] = {0,0,0,0};
  if (active){
    int c = 0;
    while (tile >= TBL.tile_off[c+1]) c++;
    int local = tile - TBL.tile_off[c];
    int n2 = TBL.nt2[c];
    int ti = local / n2, tj = local - ti*n2;
    int R = TBL.binom[8][c], C2 = TBL.binom[8][8-c];
    #pragma unroll
    for (int i=0;i<4;i++){ int r1 = ti*4+i; t1v[i] = (r1<R) ? (int)TBL.cls_masks[TBL.cls_off[c]+r1] : 0; }
    #pragma unroll
    for (int j=0;j<4;j++){ int r2 = tj*4+j; t2v[j] = (r2<C2) ? (int)TBL.cls_masks[TBL.cls_off[8-c]+r2] : 0; }
  }
  __syncthreads();   // barrier 4: P table ready

  // ---- combine: 4x4 register tile over this block's 8 s ----
  if (active){
    float2 acc[4][4] = {};
    #pragma unroll 4
    for (int s=0;s<SPH;s++){
      int swz = s << 1;
      float2 av[4], bv[4];
      #pragma unroll
      for (int i=0;i<4;i++) av[i] = P[s][t1v[i] ^ swz];
      #pragma unroll
      for (int j=0;j<4;j++) bv[j] = P[8+s][t2v[j] ^ swz];
      #pragma unroll
      for (int i=0;i<4;i++)
        #pragma unroll
        for (int j=0;j<4;j++) cmac(acc[i][j], av[i], bv[j]);
    }
    float2* dst = part + (size_t)(b*NSG + sg)*NSLOTS + (size_t)tile*16;
    #pragma unroll
    for (int i=0;i<4;i++)
      #pragma unroll
      for (int j=0;j<4;j++) dst[i*4+j] = acc[i][j];
  }
}

// ============ K2: slot-driven reduce + gemm partials ==========
// grid NP2(412) x 256. Block owns 32 consecutive slots. Now hoists 32 part
// loads per thread (2x R12's proven MLP lever); GEMM fully unrolled.
__global__ __launch_bounds__(256) void k_p2(const float* __restrict__ wgt, char* ws)
{
  __shared__ float prob[NB*SLOTS_P2];   // 256 floats
  __shared__ int   krow[SLOTS_P2];
  __shared__ float hacc[2*NB*OUTS];     // 2048 floats (8 KB)
  int tid = threadIdx.x;
  int blk = blockIdx.x;
  int slot0 = blk * SLOTS_P2;

  // ---- issue the 32 part loads FIRST (independent of krow) ----
  const float2* __restrict__ part = (const float2*)(ws + WS_PART);
  int bb_ = tid >> 5, sl_ = tid & 31;
  float2 vv[NSG];
  #pragma unroll
  for (int g=0; g<NSG; g++)
    vv[g] = part[(size_t)(bb_*NSG + g)*NSLOTS + slot0 + sl_];

  // ---- krow (overlaps with the in-flight loads) ----
  if (tid < SLOTS_P2){
    int slot = slot0 + tid;
    int tile = slot >> 4;
    int c = 0;
    while (tile >= TBL.tile_off[c+1]) c++;
    int local = tile - TBL.tile_off[c];
    int n2 = TBL.nt2[c];
    int ti = local / n2, tj = local - ti*n2;
    int r1 = ti*4 + ((slot >> 2) & 3);
    int r2 = tj*4 + (slot & 3);
    bool pad = (r1 >= TBL.binom[8][c]) || (r2 >= TBL.binom[8][8-c]);
    krow[tid] = pad ? -1 : ((const int*)(ws + WS_TMAP))[slot];
  }
  __syncthreads();

  // ---- reduce (ascending s-group order, as before) + norm partial ----
  float* __restrict__ bsum2 = (float*)(ws + WS_BSUM2);
  {
    float2 amp = make_float2(0,0);
    #pragma unroll
    for (int g=0; g<NSG; g++){ amp.x += vv[g].x; amp.y += vv[g].y; }
    float pr = (krow[sl_] >= 0) ? fmaf(amp.x, amp.x, amp.y*amp.y) : 0.0f;
    prob[bb_*SLOTS_P2 + sl_] = pr;
    float v = pr;
    #pragma unroll
    for (int off=16; off>0; off>>=1) v += __shfl_down(v, off, 32);
    if (sl_ == 0) bsum2[blk*NB + bb_] = v;
  }
  __syncthreads();

  // ---- gemm: half h owns 16 slots, thread owns column o; FULL unroll ----
  {
    int h = tid >> 7, o = tid & 127;
    float acc[NB] = {0,0,0,0,0,0,0,0};
    int sbeg = h*16;
    #pragma unroll 16
    for (int u = 0; u < 16; u++){
      int sl = sbeg + u;
      int kr = krow[sl]; if (kr < 0) kr = 0;   // prob already 0 for pads
      float wv = wgt[(size_t)kr * OUTS + o];
      #pragma unroll
      for (int b=0;b<NB;b++) acc[b] = fmaf(prob[b*SLOTS_P2 + sl], wv, acc[b]);
    }
    #pragma unroll
    for (int b=0;b<NB;b++) hacc[h*(NB*OUTS) + b*OUTS + o] = acc[b];
  }
  __syncthreads();

  float* __restrict__ pout2 = (float*)(ws + WS_POUT2);
  for (int idx = tid; idx < NB*OUTS; idx += 256)
    pout2[(size_t)blk*(NB*OUTS) + idx] = hacc[idx] + hacc[NB*OUTS + idx];
}

// ============ K3: final reduce (R12-verified) ==========
// grid NB x 1024; pout sum with 4 independent accumulators.
__global__ __launch_bounds__(1024) void k_p3(
    const float* __restrict__ bias, const char* __restrict__ ws,
    float* __restrict__ out)
{
  __shared__ float accs[8][OUTS];   // 4 KB
  __shared__ float wred[16];
  int tid = threadIdx.x, b = blockIdx.x;
  const float* __restrict__ bsum2 = (const float*)(ws + WS_BSUM2);
  const float* __restrict__ pout2 = (const float*)(ws + WS_POUT2);

  // norm: 1024-thread strided sum of NP2 entries (<=1 load each)
  float v = 0.0f;
  for (int j = tid; j < NP2; j += 1024) v += bsum2[j*NB + b];
  #pragma unroll
  for (int off=32; off>0; off>>=1) v += __shfl_down(v, off);
  if ((tid & 63) == 0) wred[tid >> 6] = v;

  // pout: group grp (0..7) sums s = grp, grp+8, ...; 4 accumulators
  int o = tid & 127, grp = tid >> 7;
  const float* __restrict__ pb = pout2 + (size_t)b*OUTS + o;
  float a0 = 0.f, a1 = 0.f, a2 = 0.f, a3 = 0.f;
  int s = grp;
  for (; s + 24 < NP2; s += 32){
    a0 += pb[(size_t)(s     )*(NB*OUTS)];
    a1 += pb[(size_t)(s +  8)*(NB*OUTS)];
    a2 += pb[(size_t)(s + 16)*(NB*OUTS)];
    a3 += pb[(size_t)(s + 24)*(NB*OUTS)];
  }
  for (; s < NP2; s += 8) a0 += pb[(size_t)s*(NB*OUTS)];
  accs[grp][o] = (a0 + a1) + (a2 + a3);
  __syncthreads();
  if (tid < OUTS){
    float norm = 0.0f;
    #pragma unroll
    for (int w=0; w<16; w++) norm += wred[w];
    float r = 0.0f;
    #pragma unroll
    for (int g=0; g<8; g++) r += accs[g][tid];
    out[b*OUTS + tid] = r / norm + bias[tid];
  }
}

// ---------------- launch ----------------
extern "C" void kernel_launch(void* const* d_in, const int* in_sizes, int n_in,
                              void* d_out, int out_size, void* d_ws, size_t ws_size,
                              hipStream_t stream) {
  const float* x    = (const float*)d_in[0];
  const float* th1  = (const float*)d_in[1];
  const float* th2  = (const float*)d_in[2];
  const float* mr   = (const float*)d_in[3];
  const float* mi   = (const float*)d_in[4];
  const float* wgt  = (const float*)d_in[5];
  const float* bias = (const float*)d_in[6];
  const int*   rows = (const int*)d_in[7];
  float* out = (float*)d_out;
  char* ws = (char*)d_ws;

  k_p1<<<NGRID, 256, 0, stream>>>(x, th1, th2, mr, mi, rows, ws);
  k_p2<<<NP2, 256, 0, stream>>>(wgt, ws);
  k_p3<<<NB, 1024, 0, stream>>>(bias, ws, out);
}

// Round 15
// 106.834 us; speedup vs baseline: 1.0280x; 1.0280x over previous
//
#include <hip/hip_runtime.h>
#include <math.h>

// ---------------- problem constants ----------------
#define NB 8          // batch
#define NM 16         // modes
#define NPH 8         // photons
#define NSTATES 12870 // C(16,8)
#define NSUB 256      // 2^NPH column subsets
#define OUTS 128
#define NTILES 824    // sum over classes of ceil(R/4)*ceil(C/4)
#define NSLOTS (NTILES*16) // 13184
#define NSG 16        // s-groups of 16
#define SPH 16        // s per producer block
#define NTG 4         // tile groups
#define TILES_PER_TG 206
#define NGRID 512     // NB * NSG * NTG
#define SLOTS_P2 32
#define NP2 412       // 412*32 == NSLOTS

// ---------------- compile-time tables ----------------
struct Tables {
  int binom[17][9];
  unsigned char cls_masks[256];
  int cls_off[10];
  int nt1[9], nt2[9];
  int tile_off[10];
};

constexpr int cpopc(int x){ int c=0; while(x){ c += x & 1; x >>= 1; } return c; }

constexpr Tables make_tables(){
  Tables t{};
  for (int n=0;n<=16;n++)
    for (int k=0;k<=8;k++){
      if (k==0) t.binom[n][k]=1;
      else if (n==0) t.binom[n][k]=0;
      else t.binom[n][k]=t.binom[n-1][k-1]+t.binom[n-1][k];
    }
  int idx=0;
  for (int p=0;p<=8;p++){
    t.cls_off[p]=idx;
    for (int m=0;m<256;m++) if (cpopc(m)==p) t.cls_masks[idx++]=(unsigned char)m;
  }
  t.cls_off[9]=idx; // 256
  int toff=0;
  for (int c=0;c<=8;c++){
    int R=t.binom[8][c], C=t.binom[8][8-c];
    t.nt1[c]=(R+3)/4; t.nt2[c]=(C+3)/4;
    t.tile_off[c]=toff; toff += t.nt1[c]*t.nt2[c];
  }
  t.tile_off[9]=toff;
  return t;
}

constexpr Tables HTBL = make_tables();
static_assert(HTBL.tile_off[9]==NTILES, "tile count");
static_assert(HTBL.cls_off[9]==256, "mask count");
__device__ const Tables TBL = HTBL;

// ---------------- workspace layout (bytes) ----------------
#define WS_TMAP   256               // NSLOTS ints = 52736 -> 52992 (pads never read)
#define WS_BSUM2  53248             // [NP2][NB] float = 13184 -> 66432
#define WS_POUT2  66560             // [NP2][NB*OUTS] float = 1687552 -> 1754112
#define WS_PART   1757184           // [NB][NSG][NSLOTS] float2 = 13500416

// ---------------- complex helpers ----------------
__device__ __forceinline__ float2 cmul(float2 a, float2 b){
  return make_float2(fmaf(a.x,b.x,-(a.y*b.y)), fmaf(a.x,b.y, a.y*b.x));
}
__device__ __forceinline__ void cmac(float2& acc, float2 a, float2 b){
  acc.x = fmaf(a.x, b.x, acc.x); acc.x = fmaf(-a.y, b.y, acc.x);
  acc.y = fmaf(a.x, b.y, acc.y); acc.y = fmaf(a.y, b.x, acc.y);
}

// ============ K1: fused setup + Ryser main (R13 4-barrier, NSG=16) =========
// grid 512 = NB(8) x NSG(16) x NTG(4); 65.1 KB LDS, 256 thr -> 2 blocks/CU.
// Part store vectorized: 8 x float4 per active thread (was 16 x float2).
__global__ __launch_bounds__(256) void k_p1(
    const float* __restrict__ x, const float* __restrict__ th1,
    const float* __restrict__ th2, const float* __restrict__ mr,
    const float* __restrict__ mi, const int* __restrict__ rows, char* ws)
{
  __shared__ float2 P[32][256];      // 64 KB; row ts = table*16+s, col swizzled
  __shared__ float2 UinL[NM][NPH];   // 1 KB  (dedicated: fill never touches)
  __shared__ float2 exL[NM];         // 128 B
  float2* __restrict__ part = (float2*)(ws + WS_PART);
  int tid = threadIdx.x;
  int blk = blockIdx.x;
  int b = blk >> 6, rest = blk & 63, sg = rest >> 2, tg = rest & 3;
  int sbase = sg * SPH;

  // prologue scratch aliased over P (all readers done by barrier 3)
  float2 (*T1)[NM]  = reinterpret_cast<float2(*)[NM]>(P[0]);
  float2 (*T2)[NM]  = reinterpret_cast<float2(*)[NM]>(P[1]);
  float2 (*Am)[NM]  = reinterpret_cast<float2(*)[NM]>(P[2]);
  float2 (*Bm)[NM]  = reinterpret_cast<float2(*)[NM]>(P[3]);

  // ---- phase A: T1/T2 + ex ----
  {
    int r = tid >> 4, cc = tid & 15;
    float sn, cs;
    sincosf(th1[r], &sn, &cs);
    float a = mr[0*256 + tid], bb = mi[0*256 + tid];
    T1[r][cc] = make_float2(cs*a - sn*bb, cs*bb + sn*a);
    sincosf(th2[r], &sn, &cs);
    float a2 = mr[2*256 + tid], b2 = mi[2*256 + tid];
    T2[r][cc] = make_float2(cs*a2 - sn*b2, cs*b2 + sn*a2);
    if (tid < NM){ float s2, c2; sincosf(x[b*NM + tid], &s2, &c2); exL[tid] = make_float2(c2, s2); }
  }
  __syncthreads();   // barrier 1

  // ---- phase B: Am/Bm with vectorized row loads ----
  {
    int r = tid >> 4, cc = tid & 15;
    float m1r[16], m1i[16], m3r[16], m3i[16];
    {
      const float4* p1r = (const float4*)(mr + 1*256 + r*16);
      const float4* p1i = (const float4*)(mi + 1*256 + r*16);
      const float4* p3r = (const float4*)(mr + 3*256 + r*16);
      const float4* p3i = (const float4*)(mi + 3*256 + r*16);
      #pragma unroll
      for (int q=0;q<4;q++){
        *(float4*)&m1r[q*4] = p1r[q];
        *(float4*)&m1i[q*4] = p1i[q];
        *(float4*)&m3r[q*4] = p3r[q];
        *(float4*)&m3i[q*4] = p3i[q];
      }
    }
    float2 accA = make_float2(0,0), accB = make_float2(0,0);
    #pragma unroll
    for (int m=0;m<NM;m++){
      cmac(accA, make_float2(m1r[m], m1i[m]), T1[m][cc]);
      cmac(accB, make_float2(m3r[m], m3i[m]), T2[m][cc]);
    }
    Am[r][cc] = accA; Bm[r][cc] = accB;
  }
  __syncthreads();   // barrier 2

  // ---- phase C: Uin with EA folded inline (bit-identical order) ----
  if (tid < NM*NPH){
    int p = tid >> 3, n = tid & 7;
    float2 acc = make_float2(0,0);
    #pragma unroll
    for (int m=0;m<NM;m++) cmac(acc, Bm[p][m], cmul(exL[m], Am[m][n]));
    UinL[p][n] = acc;
  }
  __syncthreads();   // barrier 3: scratch P[0..3] dead; UinL ready

  // ---- phase D: V-extract (UinL, dedicated) -> register-DP fill (P) ----
  int ts = tid >> 3;
  int table = ts >> 4, sl = ts & 15;
  int sv = sbase + sl;
  {
    float2 v[8];
    #pragma unroll
    for (int j=0;j<8;j++){
      float2 a = make_float2(0,0);
      int m = table*8 + j;
      #pragma unroll
      for (int jj=0;jj<NPH;jj++)
        if ((sv>>jj) & 1){ a.x += UinL[m][jj].x; a.y += UinL[m][jj].y; }
      v[j] = a;
    }
    int chunk = tid & 7;
    int t0 = chunk << 5;
    int swz = (ts & 15) << 1;
    float2 ph = make_float2((table==0 && (__popc(sv)&1)) ? -1.0f : 1.0f, 0.0f);
    if (chunk & 4) ph = cmul(ph, v[7]);
    if (chunk & 2) ph = cmul(ph, v[6]);
    if (chunk & 1) ph = cmul(ph, v[5]);

    float2 pl[16];
    // half A: u = 0..15, root ph
    pl[0] = ph;
    #pragma unroll
    for (int w=1; w<16; w++){
      int par = w & (w-1);
      int lb = (w&1) ? 0 : ((w&2) ? 1 : ((w&4) ? 2 : 3));
      pl[w] = cmul(pl[par], v[lb]);
    }
    #pragma unroll
    for (int w=0; w<16; w+=2){
      int tc = (t0 + w) ^ swz;
      *(float4*)&P[ts][tc] = make_float4(pl[w].x, pl[w].y, pl[w+1].x, pl[w+1].y);
    }
    // half B: u = 16..31, root ph*v[4]  (== original p[16])
    pl[0] = cmul(ph, v[4]);
    #pragma unroll
    for (int w=1; w<16; w++){
      int par = w & (w-1);
      int lb = (w&1) ? 0 : ((w&2) ? 1 : ((w&4) ? 2 : 3));
      pl[w] = cmul(pl[par], v[lb]);
    }
    #pragma unroll
    for (int w=0; w<16; w+=2){
      int tc = (t0 + 16 + w) ^ swz;
      *(float4*)&P[ts][tc] = make_float4(pl[w].x, pl[w].y, pl[w+1].x, pl[w+1].y);
    }
  }

  // ---- tmap ranking: hoisted (independent of P; overlaps barrier wait) ----
  if (tg == 3){
    int idx = blk >> 2;
    int kb = idx * 101;
    int ke = min(NSTATES, kb + 101);
    int k = kb + tid;
    if (k < ke){
      int t1=0, t2=0;
      #pragma unroll
      for (int i=0;i<NPH;i++){
        int rr = rows[k*NPH+i];
        if (rr < 8) t1 |= 1 << rr; else t2 |= 1 << (rr-8);
      }
      int c1 = __popc(t1);
      int rk1=0, cnt=0;
      #pragma unroll
      for (int bb=0;bb<8;bb++) if ((t1>>bb)&1){ cnt++; rk1 += TBL.binom[bb][cnt]; }
      int rk2=0; cnt=0;
      #pragma unroll
      for (int bb=0;bb<8;bb++) if ((t2>>bb)&1){ cnt++; rk2 += TBL.binom[bb][cnt]; }
      int tl = TBL.tile_off[c1] + (rk1>>2)*TBL.nt2[c1] + (rk2>>2);
      int slot = ((rk1&3)<<2) | (rk2&3);
      ((int*)(ws + WS_TMAP))[tl*16 + slot] = k;
    }
  }

  // combine-thread tile masks (registers + const tables only)
  bool active = tid < TILES_PER_TG;
  int tile = tg + 4*tid;
  int t1v[4] = {0,0,0,0}, t2v[4] = {0,0,0,0};
  if (active){
    int c = 0;
    while (tile >= TBL.tile_off[c+1]) c++;
    int local = tile - TBL.tile_off[c];
    int n2 = TBL.nt2[c];
    int ti = local / n2, tj = local - ti*n2;
    int R = TBL.binom[8][c], C2 = TBL.binom[8][8-c];
    #pragma unroll
    for (int i=0;i<4;i++){ int r1 = ti*4+i; t1v[i] = (r1<R) ? (int)TBL.cls_masks[TBL.cls_off[c]+r1] : 0; }
    #pragma unroll
    for (int j=0;j<4;j++){ int r2 = tj*4+j; t2v[j] = (r2<C2) ? (int)TBL.cls_masks[TBL.cls_off[8-c]+r2] : 0; }
  }
  __syncthreads();   // barrier 4: P table ready

  // ---- combine: 4x4 register tile over this block's 16 s ----
  if (active){
    float2 acc[4][4] = {};
    #pragma unroll 4
    for (int s=0;s<SPH;s++){
      int swz = s << 1;
      float2 av[4], bv[4];
      #pragma unroll
      for (int i=0;i<4;i++) av[i] = P[s][t1v[i] ^ swz];
      #pragma unroll
      for (int j=0;j<4;j++) bv[j] = P[16+s][t2v[j] ^ swz];
      #pragma unroll
      for (int i=0;i<4;i++)
        #pragma unroll
        for (int j=0;j<4;j++) cmac(acc[i][j], av[i], bv[j]);
    }
    // vectorized store: 16 contiguous float2 = 8 float4
    float4* dst4 = (float4*)(part + (size_t)(b*NSG + sg)*NSLOTS + (size_t)tile*16);
    #pragma unroll
    for (int i=0;i<4;i++){
      dst4[i*2+0] = make_float4(acc[i][0].x, acc[i][0].y, acc[i][1].x, acc[i][1].y);
      dst4[i*2+1] = make_float4(acc[i][2].x, acc[i][2].y, acc[i][3].x, acc[i][3].y);
    }
  }
}

// ============ K2: slot-driven reduce + gemm partials (R12-verified) ========
// grid NP2(412) x 256. Block owns 32 consecutive slots. Part loads hoisted;
// GEMM fully unrolled (16 weight-row loads in flight). pout2 write float4.
__global__ __launch_bounds__(256) void k_p2(const float* __restrict__ wgt, char* ws)
{
  __shared__ float prob[NB*SLOTS_P2];   // 256 floats
  __shared__ int   krow[SLOTS_P2];
  __shared__ float hacc[2*NB*OUTS];     // 2048 floats (8 KB)
  int tid = threadIdx.x;
  int blk = blockIdx.x;
  int slot0 = blk * SLOTS_P2;

  // ---- issue the 16 part loads FIRST (independent of krow) ----
  const float2* __restrict__ part = (const float2*)(ws + WS_PART);
  int bb_ = tid >> 5, sl_ = tid & 31;
  float2 vv[NSG];
  #pragma unroll
  for (int g=0; g<NSG; g++)
    vv[g] = part[(size_t)(bb_*NSG + g)*NSLOTS + slot0 + sl_];

  // ---- krow (overlaps with the in-flight loads) ----
  if (tid < SLOTS_P2){
    int slot = slot0 + tid;
    int tile = slot >> 4;
    int c = 0;
    while (tile >= TBL.tile_off[c+1]) c++;
    int local = tile - TBL.tile_off[c];
    int n2 = TBL.nt2[c];
    int ti = local / n2, tj = local - ti*n2;
    int r1 = ti*4 + ((slot >> 2) & 3);
    int r2 = tj*4 + (slot & 3);
    bool pad = (r1 >= TBL.binom[8][c]) || (r2 >= TBL.binom[8][8-c]);
    krow[tid] = pad ? -1 : ((const int*)(ws + WS_TMAP))[slot];
  }
  __syncthreads();

  // ---- reduce (same summation order as before) + norm partial ----
  float* __restrict__ bsum2 = (float*)(ws + WS_BSUM2);
  {
    float2 amp = make_float2(0,0);
    #pragma unroll
    for (int g=0; g<NSG; g++){ amp.x += vv[g].x; amp.y += vv[g].y; }
    float pr = (krow[sl_] >= 0) ? fmaf(amp.x, amp.x, amp.y*amp.y) : 0.0f;
    prob[bb_*SLOTS_P2 + sl_] = pr;
    float v = pr;
    #pragma unroll
    for (int off=16; off>0; off>>=1) v += __shfl_down(v, off, 32);
    if (sl_ == 0) bsum2[blk*NB + bb_] = v;
  }
  __syncthreads();

  // ---- gemm: half h owns 16 slots, thread owns column o; FULL unroll ----
  {
    int h = tid >> 7, o = tid & 127;
    float acc[NB] = {0,0,0,0,0,0,0,0};
    int sbeg = h*16;
    #pragma unroll 16
    for (int u = 0; u < 16; u++){
      int sl = sbeg + u;
      int kr = krow[sl]; if (kr < 0) kr = 0;   // prob already 0 for pads
      float wv = wgt[(size_t)kr * OUTS + o];
      #pragma unroll
      for (int b=0;b<NB;b++) acc[b] = fmaf(prob[b*SLOTS_P2 + sl], wv, acc[b]);
    }
    #pragma unroll
    for (int b=0;b<NB;b++) hacc[h*(NB*OUTS) + b*OUTS + o] = acc[b];
  }
  __syncthreads();

  // ---- pout2 write: 1024 floats / 256 threads = one float4 each ----
  {
    float* __restrict__ pout2 = (float*)(ws + WS_POUT2);
    float4 a = *(float4*)&hacc[tid*4];
    float4 c = *(float4*)&hacc[NB*OUTS + tid*4];
    *(float4*)(pout2 + (size_t)blk*(NB*OUTS) + tid*4) =
        make_float4(a.x + c.x, a.y + c.y, a.z + c.z, a.w + c.w);
  }
}

// ============ K3: final reduce (R12-verified) ==========
// grid NB x 1024; pout sum with 4 independent accumulators.
__global__ __launch_bounds__(1024) void k_p3(
    const float* __restrict__ bias, const char* __restrict__ ws,
    float* __restrict__ out)
{
  __shared__ float accs[8][OUTS];   // 4 KB
  __shared__ float wred[16];
  int tid = threadIdx.x, b = blockIdx.x;
  const float* __restrict__ bsum2 = (const float*)(ws + WS_BSUM2);
  const float* __restrict__ pout2 = (const float*)(ws + WS_POUT2);

  // norm: 1024-thread strided sum of NP2 entries (<=1 load each)
  float v = 0.0f;
  for (int j = tid; j < NP2; j += 1024) v += bsum2[j*NB + b];
  #pragma unroll
  for (int off=32; off>0; off>>=1) v += __shfl_down(v, off);
  if ((tid & 63) == 0) wred[tid >> 6] = v;

  // pout: group grp (0..7) sums s = grp, grp+8, ...; 4 accumulators
  int o = tid & 127, grp = tid >> 7;
  const float* __restrict__ pb = pout2 + (size_t)b*OUTS + o;
  float a0 = 0.f, a1 = 0.f, a2 = 0.f, a3 = 0.f;
  int s = grp;
  for (; s + 24 < NP2; s += 32){
    a0 += pb[(size_t)(s     )*(NB*OUTS)];
    a1 += pb[(size_t)(s +  8)*(NB*OUTS)];
    a2 += pb[(size_t)(s + 16)*(NB*OUTS)];
    a3 += pb[(size_t)(s + 24)*(NB*OUTS)];
  }
  for (; s < NP2; s += 8) a0 += pb[(size_t)s*(NB*OUTS)];
  accs[grp][o] = (a0 + a1) + (a2 + a3);
  __syncthreads();
  if (tid < OUTS){
    float norm = 0.0f;
    #pragma unroll
    for (int w=0; w<16; w++) norm += wred[w];
    float r = 0.0f;
    #pragma unroll
    for (int g=0; g<8; g++) r += accs[g][tid];
    out[b*OUTS + tid] = r / norm + bias[tid];
  }
}

// ---------------- launch ----------------
extern "C" void kernel_launch(void* const* d_in, const int* in_sizes, int n_in,
                              void* d_out, int out_size, void* d_ws, size_t ws_size,
                              hipStream_t stream) {
  const float* x    = (const float*)d_in[0];
  const float* th1  = (const float*)d_in[1];
  const float* th2  = (const float*)d_in[2];
  const float* mr   = (const float*)d_in[3];
  const float* mi   = (const float*)d_in[4];
  const float* wgt  = (const float*)d_in[5];
  const float* bias = (const float*)d_in[6];
  const int*   rows = (const int*)d_in[7];
  float* out = (float*)d_out;
  char* ws = (char*)d_ws;

  k_p1<<<NGRID, 256, 0, stream>>>(x, th1, th2, mr, mi, rows, ws);
  k_p2<<<NP2, 256, 0, stream>>>(wgt, ws);
  k_p3<<<NB, 1024, 0, stream>>>(bias, ws, out);
}

// Round 16
// 103.942 us; speedup vs baseline: 1.0566x; 1.0278x over previous
//
#include <hip/hip_runtime.h>
#include <math.h>

// ---------------- problem constants ----------------
#define NB 8          // batch
#define NM 16         // modes
#define NPH 8         // photons
#define NSTATES 12870 // C(16,8)
#define NSUB 256      // 2^NPH column subsets
#define OUTS 128
#define NTILES 824    // sum over classes of ceil(R/4)*ceil(C/4)
#define NSLOTS (NTILES*16) // 13184
#define NSG 16        // s-groups of 16
#define SPH 16        // s per producer block
#define NTG 4         // tile groups
#define TILES_PER_TG 206
#define NGRID 512     // NB * NSG * NTG
#define SLOTS_P2 32
#define NP2 412       // 412*32 == NSLOTS
#define PROW 264      // padded sorted row: sum over c of 4*ceil(C(8,c)/4)

// ---------------- compile-time tables ----------------
struct Tables {
  int binom[17][9];
  unsigned char cls_masks[256];
  int cls_off[10];
  int pcls_off[10];   // 4-aligned padded class offsets (sorted-P layout)
  short srt[256];     // mask -> padded sorted index
  int nt1[9], nt2[9];
  int tile_off[10];
};

constexpr int cpopc(int x){ int c=0; while(x){ c += x & 1; x >>= 1; } return c; }

constexpr Tables make_tables(){
  Tables t{};
  for (int n=0;n<=16;n++)
    for (int k=0;k<=8;k++){
      if (k==0) t.binom[n][k]=1;
      else if (n==0) t.binom[n][k]=0;
      else t.binom[n][k]=t.binom[n-1][k-1]+t.binom[n-1][k];
    }
  int idx=0;
  for (int p=0;p<=8;p++){
    t.cls_off[p]=idx;
    for (int m=0;m<256;m++) if (cpopc(m)==p) t.cls_masks[idx++]=(unsigned char)m;
  }
  t.cls_off[9]=idx; // 256
  int po=0;
  for (int p=0;p<=8;p++){ t.pcls_off[p]=po; po += ((t.binom[8][p]+3)/4)*4; }
  t.pcls_off[9]=po; // 264
  for (int i2=0;i2<256;i2++){
    int m = t.cls_masks[i2];
    int p = cpopc(m);
    t.srt[m] = (short)(t.pcls_off[p] + (i2 - t.cls_off[p]));
  }
  int toff=0;
  for (int c=0;c<=8;c++){
    int R=t.binom[8][c], C=t.binom[8][8-c];
    t.nt1[c]=(R+3)/4; t.nt2[c]=(C+3)/4;
    t.tile_off[c]=toff; toff += t.nt1[c]*t.nt2[c];
  }
  t.tile_off[9]=toff;
  return t;
}

constexpr Tables HTBL = make_tables();
static_assert(HTBL.tile_off[9]==NTILES, "tile count");
static_assert(HTBL.cls_off[9]==256, "mask count");
static_assert(HTBL.pcls_off[9]==PROW, "padded row");
__device__ const Tables TBL = HTBL;

// ---------------- workspace layout (bytes) ----------------
#define WS_TMAP   256               // NSLOTS ints = 52736 -> 52992 (pads never read)
#define WS_BSUM2  53248             // [NP2][NB] float = 13184 -> 66432
#define WS_POUT2  66560             // [NP2][NB*OUTS] float = 1687552 -> 1754112
#define WS_PART   1757184           // [NB][NSG][NSLOTS] float2 = 13500416

// ---------------- complex helpers ----------------
__device__ __forceinline__ float2 cmul(float2 a, float2 b){
  return make_float2(fmaf(a.x,b.x,-(a.y*b.y)), fmaf(a.x,b.y, a.y*b.x));
}
__device__ __forceinline__ void cmac(float2& acc, float2 a, float2 b){
  acc.x = fmaf(a.x, b.x, acc.x); acc.x = fmaf(-a.y, b.y, acc.x);
  acc.y = fmaf(a.x, b.y, acc.y); acc.y = fmaf(a.y, b.x, acc.y);
}

// ============ K1: fused setup + Ryser main, SORTED-P layout ================
// grid 512 = NB(8) x NSG(16) x NTG(4); ~67.7 KB LDS, 256 thr -> 2 blocks/CU.
// P stored sorted by (popcount, rank), classes padded to x4 (row = 264).
// Combine reads become CONTIGUOUS float4 LDS loads (2 per operand per s)
// instead of 8 random-column gathers -> kills the combine bank conflicts.
// Fill scatters through constexpr srt[mask]. Pad ranks live inside their
// class's padded region, are never written (garbage), and only ever reach
// slots k_p2 masks out (krow<0 -> pr=0). All FP orders unchanged.
__global__ __launch_bounds__(256) void k_p1(
    const float* __restrict__ x, const float* __restrict__ th1,
    const float* __restrict__ th2, const float* __restrict__ mr,
    const float* __restrict__ mi, const int* __restrict__ rows, char* ws)
{
  __shared__ float2 P[32][PROW];     // 66 KB; row ts = table*16+s, sorted cols
  __shared__ float2 UinL[NM][NPH];   // 1 KB  (dedicated)
  __shared__ float2 exL[NM];         // 128 B
  float2* __restrict__ part = (float2*)(ws + WS_PART);
  int tid = threadIdx.x;
  int blk = blockIdx.x;
  int b = blk >> 6, rest = blk & 63, sg = rest >> 2, tg = rest & 3;
  int sbase = sg * SPH;

  // prologue scratch aliased over P rows (all readers done by barrier 3)
  float2 (*T1)[NM]  = reinterpret_cast<float2(*)[NM]>(P[0]);
  float2 (*T2)[NM]  = reinterpret_cast<float2(*)[NM]>(P[1]);
  float2 (*Am)[NM]  = reinterpret_cast<float2(*)[NM]>(P[2]);
  float2 (*Bm)[NM]  = reinterpret_cast<float2(*)[NM]>(P[3]);

  // ---- phase A: T1/T2 + ex ----
  {
    int r = tid >> 4, cc = tid & 15;
    float sn, cs;
    sincosf(th1[r], &sn, &cs);
    float a = mr[0*256 + tid], bb = mi[0*256 + tid];
    T1[r][cc] = make_float2(cs*a - sn*bb, cs*bb + sn*a);
    sincosf(th2[r], &sn, &cs);
    float a2 = mr[2*256 + tid], b2 = mi[2*256 + tid];
    T2[r][cc] = make_float2(cs*a2 - sn*b2, cs*b2 + sn*a2);
    if (tid < NM){ float s2, c2; sincosf(x[b*NM + tid], &s2, &c2); exL[tid] = make_float2(c2, s2); }
  }
  __syncthreads();   // barrier 1

  // ---- phase B: Am/Bm with vectorized row loads ----
  {
    int r = tid >> 4, cc = tid & 15;
    float m1r[16], m1i[16], m3r[16], m3i[16];
    {
      const float4* p1r = (const float4*)(mr + 1*256 + r*16);
      const float4* p1i = (const float4*)(mi + 1*256 + r*16);
      const float4* p3r = (const float4*)(mr + 3*256 + r*16);
      const float4* p3i = (const float4*)(mi + 3*256 + r*16);
      #pragma unroll
      for (int q=0;q<4;q++){
        *(float4*)&m1r[q*4] = p1r[q];
        *(float4*)&m1i[q*4] = p1i[q];
        *(float4*)&m3r[q*4] = p3r[q];
        *(float4*)&m3i[q*4] = p3i[q];
      }
    }
    float2 accA = make_float2(0,0), accB = make_float2(0,0);
    #pragma unroll
    for (int m=0;m<NM;m++){
      cmac(accA, make_float2(m1r[m], m1i[m]), T1[m][cc]);
      cmac(accB, make_float2(m3r[m], m3i[m]), T2[m][cc]);
    }
    Am[r][cc] = accA; Bm[r][cc] = accB;
  }
  __syncthreads();   // barrier 2

  // ---- phase C: Uin with EA folded inline (bit-identical order) ----
  if (tid < NM*NPH){
    int p = tid >> 3, n = tid & 7;
    float2 acc = make_float2(0,0);
    #pragma unroll
    for (int m=0;m<NM;m++) cmac(acc, Bm[p][m], cmul(exL[m], Am[m][n]));
    UinL[p][n] = acc;
  }
  __syncthreads();   // barrier 3: scratch P[0..3] dead; UinL ready

  // ---- phase D: V-extract -> register-DP fill, sorted scatter ----
  int ts = tid >> 3;
  int table = ts >> 4, sl = ts & 15;
  int sv = sbase + sl;
  {
    float2 v[8];
    #pragma unroll
    for (int j=0;j<8;j++){
      float2 a = make_float2(0,0);
      int m = table*8 + j;
      #pragma unroll
      for (int jj=0;jj<NPH;jj++)
        if ((sv>>jj) & 1){ a.x += UinL[m][jj].x; a.y += UinL[m][jj].y; }
      v[j] = a;
    }
    int chunk = tid & 7;
    int t0 = chunk << 5;
    float2 ph = make_float2((table==0 && (__popc(sv)&1)) ? -1.0f : 1.0f, 0.0f);
    if (chunk & 4) ph = cmul(ph, v[7]);
    if (chunk & 2) ph = cmul(ph, v[6]);
    if (chunk & 1) ph = cmul(ph, v[5]);

    float2 pl[16];
    // half A: u = 0..15, root ph
    pl[0] = ph;
    #pragma unroll
    for (int w=1; w<16; w++){
      int par = w & (w-1);
      int lb = (w&1) ? 0 : ((w&2) ? 1 : ((w&4) ? 2 : 3));
      pl[w] = cmul(pl[par], v[lb]);
    }
    #pragma unroll
    for (int w=0; w<16; w++) P[ts][TBL.srt[t0 + w]] = pl[w];
    // half B: u = 16..31, root ph*v[4]  (== original p[16])
    pl[0] = cmul(ph, v[4]);
    #pragma unroll
    for (int w=1; w<16; w++){
      int par = w & (w-1);
      int lb = (w&1) ? 0 : ((w&2) ? 1 : ((w&4) ? 2 : 3));
      pl[w] = cmul(pl[par], v[lb]);
    }
    #pragma unroll
    for (int w=0; w<16; w++) P[ts][TBL.srt[t0 + 16 + w]] = pl[w];
  }

  // ---- tmap ranking: hoisted (independent of P; overlaps barrier wait) ----
  if (tg == 3){
    int idx = blk >> 2;
    int kb = idx * 101;
    int ke = min(NSTATES, kb + 101);
    int k = kb + tid;
    if (k < ke){
      int t1=0, t2=0;
      #pragma unroll
      for (int i=0;i<NPH;i++){
        int rr = rows[k*NPH+i];
        if (rr < 8) t1 |= 1 << rr; else t2 |= 1 << (rr-8);
      }
      int c1 = __popc(t1);
      int rk1=0, cnt=0;
      #pragma unroll
      for (int bb=0;bb<8;bb++) if ((t1>>bb)&1){ cnt++; rk1 += TBL.binom[bb][cnt]; }
      int rk2=0; cnt=0;
      #pragma unroll
      for (int bb=0;bb<8;bb++) if ((t2>>bb)&1){ cnt++; rk2 += TBL.binom[bb][cnt]; }
      int tl = TBL.tile_off[c1] + (rk1>>2)*TBL.nt2[c1] + (rk2>>2);
      int slot = ((rk1&3)<<2) | (rk2&3);
      ((int*)(ws + WS_TMAP))[tl*16 + slot] = k;
    }
  }

  // combine-thread operand bases (sorted layout: contiguous ranks)
  bool active = tid < TILES_PER_TG;
  int tile = tg + 4*tid;
  int a0 = 0, b0 = 0;
  if (active){
    int c = 0;
    while (tile >= TBL.tile_off[c+1]) c++;
    int local = tile - TBL.tile_off[c];
    int n2 = TBL.nt2[c];
    int ti = local / n2, tj = local - ti*n2;
    a0 = TBL.pcls_off[c]   + ti*4;   // multiple of 4 -> 16B-aligned float4 base
    b0 = TBL.pcls_off[8-c] + tj*4;
  }
  __syncthreads();   // barrier 4: P table ready

  // ---- combine: 4x4 register tile, contiguous float4 LDS reads ----
  if (active){
    float2 acc[4][4] = {};
    #pragma unroll 4
    for (int s=0;s<SPH;s++){
      float4 A01 = *(const float4*)&P[s][a0];
      float4 A23 = *(const float4*)&P[s][a0+2];
      float4 B01 = *(const float4*)&P[16+s][b0];
      float4 B23 = *(const float4*)&P[16+s][b0+2];
      float2 av[4] = { make_float2(A01.x,A01.y), make_float2(A01.z,A01.w),
                       make_float2(A23.x,A23.y), make_float2(A23.z,A23.w) };
      float2 bv[4] = { make_float2(B01.x,B01.y), make_float2(B01.z,B01.w),
                       make_float2(B23.x,B23.y), make_float2(B23.z,B23.w) };
      #pragma unroll
      for (int i=0;i<4;i++)
        #pragma unroll
        for (int j=0;j<4;j++) cmac(acc[i][j], av[i], bv[j]);
    }
    // vectorized store: 16 contiguous float2 = 8 float4
    float4* dst4 = (float4*)(part + (size_t)(b*NSG + sg)*NSLOTS + (size_t)tile*16);
    #pragma unroll
    for (int i=0;i<4;i++){
      dst4[i*2+0] = make_float4(acc[i][0].x, acc[i][0].y, acc[i][1].x, acc[i][1].y);
      dst4[i*2+1] = make_float4(acc[i][2].x, acc[i][2].y, acc[i][3].x, acc[i][3].y);
    }
  }
}

// ============ K2: slot-driven reduce + gemm partials (R15-verified) ========
__global__ __launch_bounds__(256) void k_p2(const float* __restrict__ wgt, char* ws)
{
  __shared__ float prob[NB*SLOTS_P2];   // 256 floats
  __shared__ int   krow[SLOTS_P2];
  __shared__ float hacc[2*NB*OUTS];     // 2048 floats (8 KB)
  int tid = threadIdx.x;
  int blk = blockIdx.x;
  int slot0 = blk * SLOTS_P2;

  // ---- issue the 16 part loads FIRST (independent of krow) ----
  const float2* __restrict__ part = (const float2*)(ws + WS_PART);
  int bb_ = tid >> 5, sl_ = tid & 31;
  float2 vv[NSG];
  #pragma unroll
  for (int g=0; g<NSG; g++)
    vv[g] = part[(size_t)(bb_*NSG + g)*NSLOTS + slot0 + sl_];

  // ---- krow (overlaps with the in-flight loads) ----
  if (tid < SLOTS_P2){
    int slot = slot0 + tid;
    int tile = slot >> 4;
    int c = 0;
    while (tile >= TBL.tile_off[c+1]) c++;
    int local = tile - TBL.tile_off[c];
    int n2 = TBL.nt2[c];
    int ti = local / n2, tj = local - ti*n2;
    int r1 = ti*4 + ((slot >> 2) & 3);
    int r2 = tj*4 + (slot & 3);
    bool pad = (r1 >= TBL.binom[8][c]) || (r2 >= TBL.binom[8][8-c]);
    krow[tid] = pad ? -1 : ((const int*)(ws + WS_TMAP))[slot];
  }
  __syncthreads();

  // ---- reduce (same summation order as before) + norm partial ----
  float* __restrict__ bsum2 = (float*)(ws + WS_BSUM2);
  {
    float2 amp = make_float2(0,0);
    #pragma unroll
    for (int g=0; g<NSG; g++){ amp.x += vv[g].x; amp.y += vv[g].y; }
    float pr = (krow[sl_] >= 0) ? fmaf(amp.x, amp.x, amp.y*amp.y) : 0.0f;
    prob[bb_*SLOTS_P2 + sl_] = pr;
    float v = pr;
    #pragma unroll
    for (int off=16; off>0; off>>=1) v += __shfl_down(v, off, 32);
    if (sl_ == 0) bsum2[blk*NB + bb_] = v;
  }
  __syncthreads();

  // ---- gemm: half h owns 16 slots, thread owns column o; FULL unroll ----
  {
    int h = tid >> 7, o = tid & 127;
    float acc[NB] = {0,0,0,0,0,0,0,0};
    int sbeg = h*16;
    #pragma unroll 16
    for (int u = 0; u < 16; u++){
      int sl = sbeg + u;
      int kr = krow[sl]; if (kr < 0) kr = 0;   // prob already 0 for pads
      float wv = wgt[(size_t)kr * OUTS + o];
      #pragma unroll
      for (int b=0;b<NB;b++) acc[b] = fmaf(prob[b*SLOTS_P2 + sl], wv, acc[b]);
    }
    #pragma unroll
    for (int b=0;b<NB;b++) hacc[h*(NB*OUTS) + b*OUTS + o] = acc[b];
  }
  __syncthreads();

  // ---- pout2 write: 1024 floats / 256 threads = one float4 each ----
  {
    float* __restrict__ pout2 = (float*)(ws + WS_POUT2);
    float4 a = *(float4*)&hacc[tid*4];
    float4 c = *(float4*)&hacc[NB*OUTS + tid*4];
    *(float4*)(pout2 + (size_t)blk*(NB*OUTS) + tid*4) =
        make_float4(a.x + c.x, a.y + c.y, a.z + c.z, a.w + c.w);
  }
}

// ============ K3: final reduce (R15-verified) ==========
__global__ __launch_bounds__(1024) void k_p3(
    const float* __restrict__ bias, const char* __restrict__ ws,
    float* __restrict__ out)
{
  __shared__ float accs[8][OUTS];   // 4 KB
  __shared__ float wred[16];
  int tid = threadIdx.x, b = blockIdx.x;
  const float* __restrict__ bsum2 = (const float*)(ws + WS_BSUM2);
  const float* __restrict__ pout2 = (const float*)(ws + WS_POUT2);

  // norm: 1024-thread strided sum of NP2 entries (<=1 load each)
  float v = 0.0f;
  for (int j = tid; j < NP2; j += 1024) v += bsum2[j*NB + b];
  #pragma unroll
  for (int off=32; off>0; off>>=1) v += __shfl_down(v, off);
  if ((tid & 63) == 0) wred[tid >> 6] = v;

  // pout: group grp (0..7) sums s = grp, grp+8, ...; 4 accumulators
  int o = tid & 127, grp = tid >> 7;
  const float* __restrict__ pb = pout2 + (size_t)b*OUTS + o;
  float a0 = 0.f, a1 = 0.f, a2 = 0.f, a3 = 0.f;
  int s = grp;
  for (; s + 24 < NP2; s += 32){
    a0 += pb[(size_t)(s     )*(NB*OUTS)];
    a1 += pb[(size_t)(s +  8)*(NB*OUTS)];
    a2 += pb[(size_t)(s + 16)*(NB*OUTS)];
    a3 += pb[(size_t)(s + 24)*(NB*OUTS)];
  }
  for (; s < NP2; s += 8) a0 += pb[(size_t)s*(NB*OUTS)];
  accs[grp][o] = (a0 + a1) + (a2 + a3);
  __syncthreads();
  if (tid < OUTS){
    float norm = 0.0f;
    #pragma unroll
    for (int w=0; w<16; w++) norm += wred[w];
    float r = 0.0f;
    #pragma unroll
    for (int g=0; g<8; g++) r += accs[g][tid];
    out[b*OUTS + tid] = r / norm + bias[tid];
  }
}

// ---------------- launch ----------------
extern "C" void kernel_launch(void* const* d_in, const int* in_sizes, int n_in,
                              void* d_out, int out_size, void* d_ws, size_t ws_size,
                              hipStream_t stream) {
  const float* x    = (const float*)d_in[0];
  const float* th1  = (const float*)d_in[1];
  const float* th2  = (const float*)d_in[2];
  const float* mr   = (const float*)d_in[3];
  const float* mi   = (const float*)d_in[4];
  const float* wgt  = (const float*)d_in[5];
  const float* bias = (const float*)d_in[6];
  const int*   rows = (const int*)d_in[7];
  float* out = (float*)d_out;
  char* ws = (char*)d_ws;

  k_p1<<<NGRID, 256, 0, stream>>>(x, th1, th2, mr, mi, rows, ws);
  k_p2<<<NP2, 256, 0, stream>>>(wgt, ws);
  k_p3<<<NB, 1024, 0, stream>>>(bias, ws, out);
}

// Round 18
// 100.936 us; speedup vs baseline: 1.0881x; 1.0298x over previous
//
#include <hip/hip_runtime.h>
#include <math.h>

// ---------------- problem constants ----------------
#define NB 8          // batch
#define NM 16         // modes
#define NPH 8         // photons
#define NSTATES 12870 // C(16,8)
#define NSUB 256      // 2^NPH column subsets
#define OUTS 128
#define NTILES 824    // sum over classes of ceil(R/4)*ceil(C/4)
#define NSLOTS (NTILES*16) // 13184
#define NSG 16        // s-groups of 16
#define SPH 16        // s per producer block
#define NTG 4         // tile groups
#define TILES_PER_TG 206
#define NGRID 512     // NB * NSG * NTG
#define SLOTS_P2 64
#define NP2 206       // 206*64 == NSLOTS
#define PROW 264      // padded sorted row: sum over c of 4*ceil(C(8,c)/4)

// ---------------- compile-time tables ----------------
struct Tables {
  int binom[17][9];
  unsigned char cls_masks[256];
  int cls_off[10];
  int pcls_off[10];   // 4-aligned padded class offsets (sorted-P layout)
  short srt[256];     // mask -> padded sorted index
  int nt1[9], nt2[9];
  int tile_off[10];
};

constexpr int cpopc(int x){ int c=0; while(x){ c += x & 1; x >>= 1; } return c; }

constexpr Tables make_tables(){
  Tables t{};
  for (int n=0;n<=16;n++)
    for (int k=0;k<=8;k++){
      if (k==0) t.binom[n][k]=1;
      else if (n==0) t.binom[n][k]=0;
      else t.binom[n][k]=t.binom[n-1][k-1]+t.binom[n-1][k];
    }
  int idx=0;
  for (int p=0;p<=8;p++){
    t.cls_off[p]=idx;
    for (int m=0;m<256;m++) if (cpopc(m)==p) t.cls_masks[idx++]=(unsigned char)m;
  }
  t.cls_off[9]=idx; // 256
  int po=0;
  for (int p=0;p<=8;p++){ t.pcls_off[p]=po; po += ((t.binom[8][p]+3)/4)*4; }
  t.pcls_off[9]=po; // 264
  for (int i2=0;i2<256;i2++){
    int m = t.cls_masks[i2];
    int p = cpopc(m);
    t.srt[m] = (short)(t.pcls_off[p] + (i2 - t.cls_off[p]));
  }
  int toff=0;
  for (int c=0;c<=8;c++){
    int R=t.binom[8][c], C=t.binom[8][8-c];
    t.nt1[c]=(R+3)/4; t.nt2[c]=(C+3)/4;
    t.tile_off[c]=toff; toff += t.nt1[c]*t.nt2[c];
  }
  t.tile_off[9]=toff;
  return t;
}

constexpr Tables HTBL = make_tables();
static_assert(HTBL.tile_off[9]==NTILES, "tile count");
static_assert(HTBL.cls_off[9]==256, "mask count");
static_assert(HTBL.pcls_off[9]==PROW, "padded row");
__device__ const Tables TBL = HTBL;

// ---------------- workspace layout (bytes) ----------------
#define WS_TMAP   256               // NSLOTS ints = 52736 -> 52992 (pads never read)
#define WS_BSUM2  53248             // [NP2][NB] float = 6592 -> 59840
#define WS_POUT2  66560             // [NP2][NB*OUTS] float = 843776 -> 910336
#define WS_PART   1757184           // [NB][NSG][NSLOTS] float2 = 13500416

// ---------------- complex helpers ----------------
__device__ __forceinline__ float2 cmul(float2 a, float2 b){
  return make_float2(fmaf(a.x,b.x,-(a.y*b.y)), fmaf(a.x,b.y, a.y*b.x));
}
__device__ __forceinline__ void cmac(float2& acc, float2 a, float2 b){
  acc.x = fmaf(a.x, b.x, acc.x); acc.x = fmaf(-a.y, b.y, acc.x);
  acc.y = fmaf(a.x, b.y, acc.y); acc.y = fmaf(a.y, b.x, acc.y);
}

// ============ K1: fused setup + Ryser main, SORTED-P layout (R16 winner) ===
// grid 512 = NB(8) x NSG(16) x NTG(4); ~67.7 KB LDS, 256 thr -> 2 blocks/CU.
__global__ __launch_bounds__(256) void k_p1(
    const float* __restrict__ x, const float* __restrict__ th1,
    const float* __restrict__ th2, const float* __restrict__ mr,
    const float* __restrict__ mi, const int* __restrict__ rows, char* ws)
{
  __shared__ float2 P[32][PROW];     // 66 KB; row ts = table*16+s, sorted cols
  __shared__ float2 UinL[NM][NPH];   // 1 KB  (dedicated)
  __shared__ float2 exL[NM];         // 128 B
  float2* __restrict__ part = (float2*)(ws + WS_PART);
  int tid = threadIdx.x;
  int blk = blockIdx.x;
  int b = blk >> 6, rest = blk & 63, sg = rest >> 2, tg = rest & 3;
  int sbase = sg * SPH;

  // prologue scratch aliased over P rows (all readers done by barrier 3)
  float2 (*T1)[NM]  = reinterpret_cast<float2(*)[NM]>(P[0]);
  float2 (*T2)[NM]  = reinterpret_cast<float2(*)[NM]>(P[1]);
  float2 (*Am)[NM]  = reinterpret_cast<float2(*)[NM]>(P[2]);
  float2 (*Bm)[NM]  = reinterpret_cast<float2(*)[NM]>(P[3]);

  // ---- phase A: T1/T2 + ex ----
  {
    int r = tid >> 4, cc = tid & 15;
    float sn, cs;
    sincosf(th1[r], &sn, &cs);
    float a = mr[0*256 + tid], bb = mi[0*256 + tid];
    T1[r][cc] = make_float2(cs*a - sn*bb, cs*bb + sn*a);
    sincosf(th2[r], &sn, &cs);
    float a2 = mr[2*256 + tid], b2 = mi[2*256 + tid];
    T2[r][cc] = make_float2(cs*a2 - sn*b2, cs*b2 + sn*a2);
    if (tid < NM){ float s2, c2; sincosf(x[b*NM + tid], &s2, &c2); exL[tid] = make_float2(c2, s2); }
  }
  __syncthreads();   // barrier 1

  // ---- phase B: Am/Bm with vectorized row loads ----
  {
    int r = tid >> 4, cc = tid & 15;
    float m1r[16], m1i[16], m3r[16], m3i[16];
    {
      const float4* p1r = (const float4*)(mr + 1*256 + r*16);
      const float4* p1i = (const float4*)(mi + 1*256 + r*16);
      const float4* p3r = (const float4*)(mr + 3*256 + r*16);
      const float4* p3i = (const float4*)(mi + 3*256 + r*16);
      #pragma unroll
      for (int q=0;q<4;q++){
        *(float4*)&m1r[q*4] = p1r[q];
        *(float4*)&m1i[q*4] = p1i[q];
        *(float4*)&m3r[q*4] = p3r[q];
        *(float4*)&m3i[q*4] = p3i[q];
      }
    }
    float2 accA = make_float2(0,0), accB = make_float2(0,0);
    #pragma unroll
    for (int m=0;m<NM;m++){
      cmac(accA, make_float2(m1r[m], m1i[m]), T1[m][cc]);
      cmac(accB, make_float2(m3r[m], m3i[m]), T2[m][cc]);
    }
    Am[r][cc] = accA; Bm[r][cc] = accB;
  }
  __syncthreads();   // barrier 2

  // ---- phase C: Uin with EA folded inline (bit-identical order) ----
  if (tid < NM*NPH){
    int p = tid >> 3, n = tid & 7;
    float2 acc = make_float2(0,0);
    #pragma unroll
    for (int m=0;m<NM;m++) cmac(acc, Bm[p][m], cmul(exL[m], Am[m][n]));
    UinL[p][n] = acc;
  }
  __syncthreads();   // barrier 3: scratch P[0..3] dead; UinL ready

  // ---- phase D: V-extract -> register-DP fill, sorted scatter ----
  int ts = tid >> 3;
  int table = ts >> 4, sl = ts & 15;
  int sv = sbase + sl;
  {
    float2 v[8];
    #pragma unroll
    for (int j=0;j<8;j++){
      float2 a = make_float2(0,0);
      int m = table*8 + j;
      #pragma unroll
      for (int jj=0;jj<NPH;jj++)
        if ((sv>>jj) & 1){ a.x += UinL[m][jj].x; a.y += UinL[m][jj].y; }
      v[j] = a;
    }
    int chunk = tid & 7;
    int t0 = chunk << 5;
    float2 ph = make_float2((table==0 && (__popc(sv)&1)) ? -1.0f : 1.0f, 0.0f);
    if (chunk & 4) ph = cmul(ph, v[7]);
    if (chunk & 2) ph = cmul(ph, v[6]);
    if (chunk & 1) ph = cmul(ph, v[5]);

    float2 pl[16];
    // half A: u = 0..15, root ph
    pl[0] = ph;
    #pragma unroll
    for (int w=1; w<16; w++){
      int par = w & (w-1);
      int lb = (w&1) ? 0 : ((w&2) ? 1 : ((w&4) ? 2 : 3));
      pl[w] = cmul(pl[par], v[lb]);
    }
    #pragma unroll
    for (int w=0; w<16; w++) P[ts][TBL.srt[t0 + w]] = pl[w];
    // half B: u = 16..31, root ph*v[4]  (== original p[16])
    pl[0] = cmul(ph, v[4]);
    #pragma unroll
    for (int w=1; w<16; w++){
      int par = w & (w-1);
      int lb = (w&1) ? 0 : ((w&2) ? 1 : ((w&4) ? 2 : 3));
      pl[w] = cmul(pl[par], v[lb]);
    }
    #pragma unroll
    for (int w=0; w<16; w++) P[ts][TBL.srt[t0 + 16 + w]] = pl[w];
  }

  // ---- tmap ranking: hoisted (independent of P; overlaps barrier wait) ----
  if (tg == 3){
    int idx = blk >> 2;
    int kb = idx * 101;
    int ke = min(NSTATES, kb + 101);
    int k = kb + tid;
    if (k < ke){
      int t1=0, t2=0;
      #pragma unroll
      for (int i=0;i<NPH;i++){
        int rr = rows[k*NPH+i];
        if (rr < 8) t1 |= 1 << rr; else t2 |= 1 << (rr-8);
      }
      int c1 = __popc(t1);
      int rk1=0, cnt=0;
      #pragma unroll
      for (int bb=0;bb<8;bb++) if ((t1>>bb)&1){ cnt++; rk1 += TBL.binom[bb][cnt]; }
      int rk2=0; cnt=0;
      #pragma unroll
      for (int bb=0;bb<8;bb++) if ((t2>>bb)&1){ cnt++; rk2 += TBL.binom[bb][cnt]; }
      int tl = TBL.tile_off[c1] + (rk1>>2)*TBL.nt2[c1] + (rk2>>2);
      int slot = ((rk1&3)<<2) | (rk2&3);
      ((int*)(ws + WS_TMAP))[tl*16 + slot] = k;
    }
  }

  // combine-thread operand bases (sorted layout: contiguous ranks)
  bool active = tid < TILES_PER_TG;
  int tile = tg + 4*tid;
  int a0 = 0, b0 = 0;
  if (active){
    int c = 0;
    while (tile >= TBL.tile_off[c+1]) c++;
    int local = tile - TBL.tile_off[c];
    int n2 = TBL.nt2[c];
    int ti = local / n2, tj = local - ti*n2;
    a0 = TBL.pcls_off[c]   + ti*4;   // multiple of 4 -> 16B-aligned float4 base
    b0 = TBL.pcls_off[8-c] + tj*4;
  }
  __syncthreads();   // barrier 4: P table ready

  // ---- combine: 4x4 register tile, contiguous float4 LDS reads ----
  if (active){
    float2 acc[4][4] = {};
    #pragma unroll 4
    for (int s=0;s<SPH;s++){
      float4 A01 = *(const float4*)&P[s][a0];
      float4 A23 = *(const float4*)&P[s][a0+2];
      float4 B01 = *(const float4*)&P[16+s][b0];
      float4 B23 = *(const float4*)&P[16+s][b0+2];
      float2 av[4] = { make_float2(A01.x,A01.y), make_float2(A01.z,A01.w),
                       make_float2(A23.x,A23.y), make_float2(A23.z,A23.w) };
      float2 bv[4] = { make_float2(B01.x,B01.y), make_float2(B01.z,B01.w),
                       make_float2(B23.x,B23.y), make_float2(B23.z,B23.w) };
      #pragma unroll
      for (int i=0;i<4;i++)
        #pragma unroll
        for (int j=0;j<4;j++) cmac(acc[i][j], av[i], bv[j]);
    }
    // vectorized store: 16 contiguous float2 = 8 float4
    float4* dst4 = (float4*)(part + (size_t)(b*NSG + sg)*NSLOTS + (size_t)tile*16);
    #pragma unroll
    for (int i=0;i<4;i++){
      dst4[i*2+0] = make_float4(acc[i][0].x, acc[i][0].y, acc[i][1].x, acc[i][1].y);
      dst4[i*2+1] = make_float4(acc[i][2].x, acc[i][2].y, acc[i][3].x, acc[i][3].y);
    }
  }
}

// ============ K2: 206 blocks x 512 threads, 64 slots/block ==========
// Same per-thread MLP as R12/R15 (16 hoisted part loads, 16-deep full-unroll
// weight GEMM) with half the block launches and half the pout2 partials.
// Norm reduce is a clean full-wave shfl (b == wave index).
__global__ __launch_bounds__(512) void k_p2(const float* __restrict__ wgt, char* ws)
{
  __shared__ float prob[NB*SLOTS_P2];   // 512 floats
  __shared__ int   krow[SLOTS_P2];      // 64
  __shared__ float hacc[4*NB*OUTS];     // 4096 floats (16 KB)
  int tid = threadIdx.x;
  int blk = blockIdx.x;
  int slot0 = blk * SLOTS_P2;

  // ---- issue the 16 part loads FIRST (independent of krow) ----
  const float2* __restrict__ part = (const float2*)(ws + WS_PART);
  int bb_ = tid >> 6, sl_ = tid & 63;   // b = wave index
  float2 vv[NSG];
  #pragma unroll
  for (int g=0; g<NSG; g++)
    vv[g] = part[(size_t)(bb_*NSG + g)*NSLOTS + slot0 + sl_];

  // ---- krow (overlaps with the in-flight loads) ----
  if (tid < SLOTS_P2){
    int slot = slot0 + tid;
    int tile = slot >> 4;
    int c = 0;
    while (tile >= TBL.tile_off[c+1]) c++;
    int local = tile - TBL.tile_off[c];
    int n2 = TBL.nt2[c];
    int ti = local / n2, tj = local - ti*n2;
    int r1 = ti*4 + ((slot >> 2) & 3);
    int r2 = tj*4 + (slot & 3);
    bool pad = (r1 >= TBL.binom[8][c]) || (r2 >= TBL.binom[8][8-c]);
    krow[tid] = pad ? -1 : ((const int*)(ws + WS_TMAP))[slot];
  }
  __syncthreads();

  // ---- reduce (ascending g order, as before) + full-wave norm partial ----
  float* __restrict__ bsum2 = (float*)(ws + WS_BSUM2);
  {
    float2 amp = make_float2(0,0);
    #pragma unroll
    for (int g=0; g<NSG; g++){ amp.x += vv[g].x; amp.y += vv[g].y; }
    float pr = (krow[sl_] >= 0) ? fmaf(amp.x, amp.x, amp.y*amp.y) : 0.0f;
    prob[bb_*SLOTS_P2 + sl_] = pr;
    float v = pr;
    #pragma unroll
    for (int off=32; off>0; off>>=1) v += __shfl_down(v, off);
    if (sl_ == 0) bsum2[blk*NB + bb_] = v;
  }
  __syncthreads();

  // ---- gemm: quarter q owns 16 slots, thread owns column o; FULL unroll ----
  {
    int q = tid >> 7, o = tid & 127;
    float acc[NB] = {0,0,0,0,0,0,0,0};
    int sbeg = q*16;
    #pragma unroll 16
    for (int u = 0; u < 16; u++){
      int sl = sbeg + u;
      int kr = krow[sl]; if (kr < 0) kr = 0;   // prob already 0 for pads
      float wv = wgt[(size_t)kr * OUTS + o];
      #pragma unroll
      for (int b=0;b<NB;b++) acc[b] = fmaf(prob[b*SLOTS_P2 + sl], wv, acc[b]);
    }
    #pragma unroll
    for (int b=0;b<NB;b++) hacc[q*(NB*OUTS) + b*OUTS + o] = acc[b];
  }
  __syncthreads();

  // ---- pout2 write: sum 4 quarters, float2 per thread ----
  {
    float* __restrict__ pout2 = (float*)(ws + WS_POUT2);
    int i0 = tid*2;
    float2 a = *(float2*)&hacc[i0];
    float2 c1 = *(float2*)&hacc[NB*OUTS + i0];
    float2 c2 = *(float2*)&hacc[2*NB*OUTS + i0];
    float2 c3 = *(float2*)&hacc[3*NB*OUTS + i0];
    *(float2*)(pout2 + (size_t)blk*(NB*OUTS) + i0) =
        make_float2((a.x + c1.x) + (c2.x + c3.x), (a.y + c1.y) + (c2.y + c3.y));
  }
}

// ============ K3: final reduce ==========
// grid NB x 1024; pout sum with 4 independent accumulators over 206 partials.
__global__ __launch_bounds__(1024) void k_p3(
    const float* __restrict__ bias, const char* __restrict__ ws,
    float* __restrict__ out)
{
  __shared__ float accs[8][OUTS];   // 4 KB
  __shared__ float wred[16];
  int tid = threadIdx.x, b = blockIdx.x;
  const float* __restrict__ bsum2 = (const float*)(ws + WS_BSUM2);
  const float* __restrict__ pout2 = (const float*)(ws + WS_POUT2);

  // norm: 1024-thread strided sum of NP2 entries (<=1 load each)
  float v = 0.0f;
  for (int j = tid; j < NP2; j += 1024) v += bsum2[j*NB + b];
  #pragma unroll
  for (int off=32; off>0; off>>=1) v += __shfl_down(v, off);
  if ((tid & 63) == 0) wred[tid >> 6] = v;

  // pout: group grp (0..7) sums s = grp, grp+8, ...; 4 accumulators
  int o = tid & 127, grp = tid >> 7;
  const float* __restrict__ pb = pout2 + (size_t)b*OUTS + o;
  float a0 = 0.f, a1 = 0.f, a2 = 0.f, a3 = 0.f;
  int s = grp;
  for (; s + 24 < NP2; s += 32){
    a0 += pb[(size_t)(s     )*(NB*OUTS)];
    a1 += pb[(size_t)(s +  8)*(NB*OUTS)];
    a2 += pb[(size_t)(s + 16)*(NB*OUTS)];
    a3 += pb[(size_t)(s + 24)*(NB*OUTS)];
  }
  for (; s < NP2; s += 8) a0 += pb[(size_t)s*(NB*OUTS)];
  accs[grp][o] = (a0 + a1) + (a2 + a3);
  __syncthreads();
  if (tid < OUTS){
    float norm = 0.0f;
    #pragma unroll
    for (int w=0; w<16; w++) norm += wred[w];
    float r = 0.0f;
    #pragma unroll
    for (int g=0; g<8; g++) r += accs[g][tid];
    out[b*OUTS + tid] = r / norm + bias[tid];
  }
}

// ---------------- launch ----------------
extern "C" void kernel_launch(void* const* d_in, const int* in_sizes, int n_in,
                              void* d_out, int out_size, void* d_ws, size_t ws_size,
                              hipStream_t stream) {
  const float* x    = (const float*)d_in[0];
  const float* th1  = (const float*)d_in[1];
  const float* th2  = (const float*)d_in[2];
  const float* mr   = (const float*)d_in[3];
  const float* mi   = (const float*)d_in[4];
  const float* wgt  = (const float*)d_in[5];
  const float* bias = (const float*)d_in[6];
  const int*   rows = (const int*)d_in[7];
  float* out = (float*)d_out;
  char* ws = (char*)d_ws;

  k_p1<<<NGRID, 256, 0, stream>>>(x, th1, th2, mr, mi, rows, ws);
  k_p2<<<NP2, 512, 0, stream>>>(wgt, ws);
  k_p3<<<NB, 1024, 0, stream>>>(bias, ws, out);
}